// Round 7
// baseline (640.148 us; speedup 1.0000x reference)
//
#include <hip/hip_runtime.h>
#include <math.h>

#define T_SEQ  512
#define HID    128
#define G3     384   // 3*HID, gate order r,z,n
#define NL     4
#define CHUNK  8
#define NCHUNK (T_SEQ / CHUNK)   // 64

// workspace layout (float offsets)
#define GI_TOT   (NL * T_SEQ * G3)
#define SEQ_TOT  (NL * T_SEQ * HID)
#define FLAG_OFF (GI_TOT + SEQ_TOT)

__device__ __forceinline__ float fsig(float x) {
    float e = __expf(-x);
    return 1.0f / (1.0f + e);
}
__device__ __forceinline__ float ftanh(float x) {
    float ax = fabsf(x);
    float e = __expf(-2.0f * ax);
    float t = (1.0f - e) / (1.0f + e);
    return copysignf(t, x);
}

// ---------------- init: reset handoff flags ----------------
__global__ void init_flags(int* fl) {
    int i = threadIdx.x;
    if (i < 8) fl[i * 16] = (i == 0) ? NCHUNK : 0;  // gi0 fully ready
}

// ---------------- layer-0 gi ----------------
__global__ void gi0_kernel(const float* __restrict__ x, const float* __restrict__ Wih0,
                           const float* __restrict__ bih, float* __restrict__ gi) {
    int t = blockIdx.x;
    int g = threadIdx.x;
    float x0 = x[t * 2048 + 1023];
    float x1 = x[t * 2048 + 1024 + 1023];
    gi[t * G3 + g] = bih[g] + Wih0[g * 2 + 0] * x0 + Wih0[g * 2 + 1] * x1;
}

// ---------------- persistent pipeline: 7 blocks x 256 threads ----------------
// bid 0,2,4,6 -> rec layer bid/2 ; bid 1,3,5 -> gi layer (bid+1)/2
// rec decomposition (j-owner): j = wave*32 + (lane>>1), kh = lane&1 (K-half).
// Thread computes rows {j, 128+j, 256+j} over its 64-wide K-half (192 FMAs),
// pair-reduces via __shfl_xor(.,1), does gates redundantly on both lanes,
// kh==0 writes h into double-buffered h_s -> ONE barrier/step, no LDS ps.
__global__ __launch_bounds__(256, 1) void pipe_kernel(float* __restrict__ ws,
                                                      const float* __restrict__ WihR,
                                                      const float* __restrict__ bih,
                                                      const float* __restrict__ Whh,
                                                      const float* __restrict__ bhh) {
    __shared__ float smem[2688];
    float* h_s  = smem;          // [256]   rec: double-buffered h
    float* ps   = smem + 128;    // [1536]  gi role only (overlaps h_s tail unused by gi)
    float* aux  = smem + 1664;   // [1024]  hist (rec) / staged seq (gi)

    int bid  = blockIdx.x;
    int tid  = threadIdx.x;
    int* fl = (int*)(ws + FLAG_OFF);
    bool is_rec = (bid & 1) == 0;
    int  l      = is_rec ? (bid >> 1) : ((bid + 1) >> 1);

    if (is_rec) {
        // ---------------- rec role: layer l ----------------
        const float* W   = Whh + (size_t)l * G3 * HID;
        const float* gi  = ws + (size_t)l * T_SEQ * G3;
        float* seq_o     = ws + GI_TOT + (size_t)l * T_SEQ * HID;
        int* in_flag     = &fl[l * 16];
        int* out_flag    = &fl[(4 + l) * 16];

        int lane = tid & 63;
        int wv   = tid >> 6;
        int j    = wv * 32 + (lane >> 1);   // output index 0..127
        int kh   = lane & 1;                // K-half

        // rows j, 128+j, 256+j ; cols kh*64..kh*64+63  -> 192 floats
        float w[3][64];
#pragma unroll
        for (int r = 0; r < 3; r++) {
            const float4* wr = reinterpret_cast<const float4*>(
                W + (size_t)(r * HID + j) * HID + kh * 64);
#pragma unroll
            for (int c = 0; c < 16; c++) {
                float4 v = wr[c];
                w[r][c * 4 + 0] = v.x; w[r][c * 4 + 1] = v.y;
                w[r][c * 4 + 2] = v.z; w[r][c * 4 + 3] = v.w;
            }
        }
        const float* bb = bhh + (size_t)l * G3;
        float br = bb[j], bz = bb[HID + j], bn = bb[2 * HID + j];

        float hprev = 0.0f;
        float gir = 0.f, giz = 0.f, gin = 0.f;
        float n_gir = 0.f, n_giz = 0.f, n_gin = 0.f;
        if (tid < HID) h_s[tid] = 0.0f;   // zero buffer 0
        __syncthreads();

        for (int c = 0; c < NCHUNK; c++) {
            if (tid == 0) {
                while (__hip_atomic_load(in_flag, __ATOMIC_ACQUIRE, __HIP_MEMORY_SCOPE_AGENT) < c + 1)
                    __builtin_amdgcn_s_sleep(2);
            }
            __syncthreads();
            int t0 = c * CHUNK;
            {   // first-step gi load
                const float* gp = gi + (size_t)t0 * G3;
                gir = gp[j]; giz = gp[HID + j]; gin = gp[2 * HID + j];
            }
            for (int s = 0; s < CHUNK; s++) {
                int t = t0 + s;
                if (s + 1 < CHUNK) {   // prefetch next step's gi under the matvec
                    const float* gp = gi + (size_t)(t + 1) * G3;
                    n_gir = gp[j]; n_giz = gp[HID + j]; n_gin = gp[2 * HID + j];
                }
                // matvec: 3 rows x 64 K
                const float4* h4 = reinterpret_cast<const float4*>(h_s + (t & 1) * HID + kh * 64);
                float ar = 0.f, az = 0.f, an = 0.f;
#pragma unroll
                for (int cc = 0; cc < 16; cc++) {
                    float4 hv = h4[cc];
                    ar += w[0][cc*4+0]*hv.x + w[0][cc*4+1]*hv.y + w[0][cc*4+2]*hv.z + w[0][cc*4+3]*hv.w;
                    az += w[1][cc*4+0]*hv.x + w[1][cc*4+1]*hv.y + w[1][cc*4+2]*hv.z + w[1][cc*4+3]*hv.w;
                    an += w[2][cc*4+0]*hv.x + w[2][cc*4+1]*hv.y + w[2][cc*4+2]*hv.z + w[2][cc*4+3]*hv.w;
                }
                // pair reduce (lanes 2m <-> 2m+1); fp add commutes -> both lanes identical
                ar += __shfl_xor(ar, 1, 64);
                az += __shfl_xor(az, 1, 64);
                an += __shfl_xor(an, 1, 64);
                float r_ = fsig(gir + ar + br);
                float z_ = fsig(giz + az + bz);
                float n_ = ftanh(gin + r_ * (an + bn));
                float hn = (1.0f - z_) * n_ + z_ * hprev;
                hprev = hn;
                if (kh == 0) {
                    h_s[((t + 1) & 1) * HID + j] = hn;
                    aux[s * HID + j] = hn;
                }
                gir = n_gir; giz = n_giz; gin = n_gin;
                __syncthreads();
            }
            // chunk flush: coalesced write of CHUNK*128 floats
            {
                float4 v = *reinterpret_cast<const float4*>(&aux[tid * 4]);
                *reinterpret_cast<float4*>(&seq_o[(size_t)t0 * HID + tid * 4]) = v;
            }
            __threadfence();
            __syncthreads();
            if (tid == 0)
                __hip_atomic_store(out_flag, c + 1, __ATOMIC_RELEASE, __HIP_MEMORY_SCOPE_AGENT);
        }
    } else {
        // ---------------- gi role: layer l (1..3) — R4-proven code ----------------
        const float* W   = WihR + (size_t)(l - 1) * G3 * HID;
        const float* seq_in = ws + GI_TOT + (size_t)(l - 1) * T_SEQ * HID;
        float* gi_o      = ws + (size_t)l * T_SEQ * G3;
        int* in_flag     = &fl[(4 + (l - 1)) * 16];
        int* out_flag    = &fl[l * 16];

        int q    = tid >> 6;     // wave = K-quarter
        int rg   = tid & 63;
        int row0 = rg * 6;

        float w[6][32];
        const float* wbase = W + q * 32;
#pragma unroll
        for (int i = 0; i < 6; i++) {
            const float4* wr = reinterpret_cast<const float4*>(wbase + (size_t)(row0 + i) * HID);
#pragma unroll
            for (int c = 0; c < 8; c++) {
                float4 v = wr[c];
                w[i][c * 4 + 0] = v.x; w[i][c * 4 + 1] = v.y;
                w[i][c * 4 + 2] = v.z; w[i][c * 4 + 3] = v.w;
            }
        }
        float br = 0.f, bz = 0.f, bn = 0.f;
        if (tid < HID) {
            const float* bb = bih + (size_t)l * G3;
            br = bb[tid]; bz = bb[HID + tid]; bn = bb[2 * HID + tid];
        }

        for (int c = 0; c < NCHUNK; c++) {
            if (tid == 0) {
                while (__hip_atomic_load(in_flag, __ATOMIC_ACQUIRE, __HIP_MEMORY_SCOPE_AGENT) < c + 1)
                    __builtin_amdgcn_s_sleep(2);
            }
            __syncthreads();
            int t0 = c * CHUNK;
            {   // stage seq chunk (1024 floats)
                float4 v = *reinterpret_cast<const float4*>(&seq_in[(size_t)t0 * HID + tid * 4]);
                *reinterpret_cast<float4*>(&aux[tid * 4]) = v;
            }
            __syncthreads();
            for (int s = 0; s < CHUNK; s++) {
                int t = t0 + s;
                const float4* h4 = reinterpret_cast<const float4*>(aux + s * HID + q * 32);
                float4 hv[8];
#pragma unroll
                for (int cc = 0; cc < 8; cc++) hv[cc] = h4[cc];
                float acc[6];
#pragma unroll
                for (int i = 0; i < 6; i++) {
                    float a0 = 0.f, a1 = 0.f;
#pragma unroll
                    for (int cc = 0; cc < 8; cc += 2) {
                        float4 v0 = hv[cc], v1 = hv[cc + 1];
                        a0 += w[i][cc*4+0]*v0.x + w[i][cc*4+1]*v0.y + w[i][cc*4+2]*v0.z + w[i][cc*4+3]*v0.w;
                        a1 += w[i][cc*4+4]*v1.x + w[i][cc*4+5]*v1.y + w[i][cc*4+6]*v1.z + w[i][cc*4+7]*v1.w;
                    }
                    acc[i] = a0 + a1;
                }
#pragma unroll
                for (int i = 0; i < 6; i += 2) {
                    float2 p; p.x = acc[i]; p.y = acc[i + 1];
                    *reinterpret_cast<float2*>(&ps[q * G3 + row0 + i]) = p;
                }
                __syncthreads();
                if (tid < HID) {
                    int jj = tid;
                    float vr = (ps[jj]         + ps[G3 + jj])         + (ps[2*G3 + jj]         + ps[3*G3 + jj]);
                    float vz = (ps[HID + jj]   + ps[G3 + HID + jj])   + (ps[2*G3 + HID + jj]   + ps[3*G3 + HID + jj]);
                    float vn = (ps[2*HID + jj] + ps[G3 + 2*HID + jj]) + (ps[2*G3 + 2*HID + jj] + ps[3*G3 + 2*HID + jj]);
                    float* gp = gi_o + (size_t)t * G3;
                    gp[jj]           = vr + br;
                    gp[HID + jj]     = vz + bz;
                    gp[2 * HID + jj] = vn + bn;
                }
                __syncthreads();
            }
            __threadfence();
            __syncthreads();
            if (tid == 0)
                __hip_atomic_store(out_flag, c + 1, __ATOMIC_RELEASE, __HIP_MEMORY_SCOPE_AGENT);
        }
    }
}

// ---------------- FC head ----------------
__global__ void fc_kernel(const float* __restrict__ seq, const float* __restrict__ fc1w,
                          const float* __restrict__ fc1b, const float* __restrict__ fc2w,
                          const float* __restrict__ fc2b, float* __restrict__ out) {
    __shared__ float h3[HID];
    __shared__ float hid[HID];
    int t = blockIdx.x;
    int i = threadIdx.x;
    h3[i] = seq[t * HID + i];
    __syncthreads();
    const float4* w4 = reinterpret_cast<const float4*>(fc1w + i * HID);
    const float4* h4 = reinterpret_cast<const float4*>(h3);
    float a0 = 0.f, a1 = 0.f, a2 = 0.f, a3 = 0.f;
#pragma unroll
    for (int k = 0; k < 32; k += 4) {
        float4 w0 = w4[k], w1 = w4[k + 1], w2 = w4[k + 2], w3 = w4[k + 3];
        float4 h0 = h4[k], h1 = h4[k + 1], h2 = h4[k + 2], h3v = h4[k + 3];
        a0 += w0.x * h0.x + w0.y * h0.y + w0.z * h0.z + w0.w * h0.w;
        a1 += w1.x * h1.x + w1.y * h1.y + w1.z * h1.z + w1.w * h1.w;
        a2 += w2.x * h2.x + w2.y * h2.y + w2.z * h2.z + w2.w * h2.w;
        a3 += w3.x * h3v.x + w3.y * h3v.y + w3.z * h3v.z + w3.w * h3v.w;
    }
    float v = fc1b[i] + ((a0 + a1) + (a2 + a3));
    hid[i] = v > 0.0f ? v : 0.0f;
    __syncthreads();
    if (i < 3) {
        const float* w = fc2w + i * HID;
        float s = 0.f;
#pragma unroll
        for (int k = 0; k < HID; k++) s += w[k] * hid[k];
        out[t * 3 + i] = fc2b[i] + s;
    }
}

extern "C" void kernel_launch(void* const* d_in, const int* in_sizes, int n_in,
                              void* d_out, int out_size, void* d_ws, size_t ws_size,
                              hipStream_t stream) {
    const float* x     = (const float*)d_in[0];
    const float* Wih0  = (const float*)d_in[1];
    const float* WihR  = (const float*)d_in[2];   // (3, 384, 128)
    const float* Whh   = (const float*)d_in[3];   // (4, 384, 128)
    const float* bih   = (const float*)d_in[4];   // (4, 384)
    const float* bhh   = (const float*)d_in[5];   // (4, 384)
    const float* fc1w  = (const float*)d_in[6];
    const float* fc1b  = (const float*)d_in[7];
    const float* fc2w  = (const float*)d_in[8];
    const float* fc2b  = (const float*)d_in[9];
    float* out = (float*)d_out;
    float* ws  = (float*)d_ws;

    int*   flags = (int*)(ws + FLAG_OFF);
    float* gi0   = ws;
    float* seq3  = ws + GI_TOT + (size_t)3 * T_SEQ * HID;

    init_flags<<<1, 64, 0, stream>>>(flags);
    gi0_kernel<<<T_SEQ, G3, 0, stream>>>(x, Wih0, bih, gi0);
    pipe_kernel<<<7, 256, 0, stream>>>(ws, WihR, bih, Whh, bhh);
    fc_kernel<<<T_SEQ, HID, 0, stream>>>(seq3, fc1w, fc1b, fc2w, fc2b, out);
}

// Round 8
// 474.160 us; speedup vs baseline: 1.3501x; 1.3501x over previous
//
#include <hip/hip_runtime.h>
#include <math.h>

#define T_SEQ  512
#define HID    128
#define G3     384   // 3*HID, gate order r,z,n
#define NL     4
#define CHUNK  8
#define NCHUNK (T_SEQ / CHUNK)   // 64

// workspace layout (float offsets)
#define GI_TOT   (NL * T_SEQ * G3)
#define SEQ_TOT  (NL * T_SEQ * HID)
#define FLAG_OFF (GI_TOT + SEQ_TOT)

__device__ __forceinline__ float fsig(float x) {
    float e = __expf(-x);
    return 1.0f / (1.0f + e);
}
__device__ __forceinline__ float ftanh(float x) {
    float ax = fabsf(x);
    float e = __expf(-2.0f * ax);
    float t = (1.0f - e) / (1.0f + e);
    return copysignf(t, x);
}

// Handoff protocol (invalidate-free):
//  - writer: normal stores, then RELEASE agent atomic store of the flag
//    (waitcnt + L2 writeback precede the flag reaching the LLC -> data at LLC first).
//  - reader: spins with RELAXED agent atomic load (sc-bypass load reads the LLC,
//    emits NO buffer_inv). Data loads are plain: every data address is first-touch
//    within this dispatch (dispatch start invalidated caches), so the miss fetches
//    the fresh line from LLC. An ACQUIRE here would buffer_inv the whole L1/L2 per
//    chunk -- measured as 5.5x FETCH_SIZE and +600 cyc/step in R4-R6.

// ---------------- init: reset handoff flags ----------------
__global__ void init_flags(int* fl) {
    int i = threadIdx.x;
    if (i < 8) fl[i * 16] = (i == 0) ? NCHUNK : 0;  // gi0 fully ready
}

// ---------------- layer-0 gi ----------------
__global__ void gi0_kernel(const float* __restrict__ x, const float* __restrict__ Wih0,
                           const float* __restrict__ bih, float* __restrict__ gi) {
    int t = blockIdx.x;
    int g = threadIdx.x;
    float x0 = x[t * 2048 + 1023];
    float x1 = x[t * 2048 + 1024 + 1023];
    gi[t * G3 + g] = bih[g] + Wih0[g * 2 + 0] * x0 + Wih0[g * 2 + 1] * x1;
}

// ---------------- persistent pipeline: 7 blocks x 256 threads (R4 structure) ----------------
// bid 0,2,4,6 -> rec layer bid/2 ; bid 1,3,5 -> gi layer (bid+1)/2
__global__ __launch_bounds__(256, 1) void pipe_kernel(float* __restrict__ ws,
                                                      const float* __restrict__ WihR,
                                                      const float* __restrict__ bih,
                                                      const float* __restrict__ Whh,
                                                      const float* __restrict__ bhh) {
    __shared__ float smem[2688];
    float* h_s  = smem;          // [128]   (rec)
    float* ps   = smem + 128;    // [1536]  (both)
    float* aux  = smem + 1664;   // [1024]  hist (rec) / xs (gi)

    int bid = blockIdx.x;
    int tid = threadIdx.x;
    int q   = tid >> 6;          // wave = K-quarter
    int rg  = tid & 63;
    int row0 = rg * 6;
    int* fl = (int*)(ws + FLAG_OFF);
    bool is_rec = (bid & 1) == 0;
    int  l      = is_rec ? (bid >> 1) : ((bid + 1) >> 1);

    if (is_rec) {
        // ---------------- rec role: layer l ----------------
        const float* W   = Whh + (size_t)l * G3 * HID;
        const float* gi  = ws + (size_t)l * T_SEQ * G3;
        float* seq_o     = ws + GI_TOT + (size_t)l * T_SEQ * HID;
        int* in_flag     = &fl[l * 16];            // gi_l chunks ready
        int* out_flag    = &fl[(4 + l) * 16];      // seq_l chunks ready

        float w[6][32];
        const float* wbase = W + q * 32;
#pragma unroll
        for (int i = 0; i < 6; i++) {
            const float4* wr = reinterpret_cast<const float4*>(wbase + (size_t)(row0 + i) * HID);
#pragma unroll
            for (int c = 0; c < 8; c++) {
                float4 v = wr[c];
                w[i][c * 4 + 0] = v.x; w[i][c * 4 + 1] = v.y;
                w[i][c * 4 + 2] = v.z; w[i][c * 4 + 3] = v.w;
            }
        }

        float hprev = 0.f, br = 0.f, bz = 0.f, bn = 0.f;
        float gir = 0.f, giz = 0.f, gin = 0.f;
        float n_gir = 0.f, n_giz = 0.f, n_gin = 0.f;
        if (tid < HID) {
            h_s[tid] = 0.0f;
            const float* bb = bhh + (size_t)l * G3;
            br = bb[tid]; bz = bb[HID + tid]; bn = bb[2 * HID + tid];
        }
        __syncthreads();

        for (int c = 0; c < NCHUNK; c++) {
            if (tid == 0) {
                while (__hip_atomic_load(in_flag, __ATOMIC_RELAXED, __HIP_MEMORY_SCOPE_AGENT) < c + 1)
                    __builtin_amdgcn_s_sleep(2);
            }
            __syncthreads();
            int t0 = c * CHUNK;
            if (tid < HID) {  // first-step gi load (once per chunk)
                const float* gp = gi + (size_t)t0 * G3;
                gir = gp[tid]; giz = gp[HID + tid]; gin = gp[2 * HID + tid];
            }
            for (int s = 0; s < CHUNK; s++) {
                int t = t0 + s;
                // issue next-step gi prefetch early (hides under matvec)
                if (tid < HID && s + 1 < CHUNK) {
                    const float* gp = gi + (size_t)(t + 1) * G3;
                    n_gir = gp[tid]; n_giz = gp[HID + tid]; n_gin = gp[2 * HID + tid];
                }
                // phase 1: partial matvec
                const float4* h4 = reinterpret_cast<const float4*>(h_s + q * 32);
                float4 hv[8];
#pragma unroll
                for (int cc = 0; cc < 8; cc++) hv[cc] = h4[cc];
                float acc[6];
#pragma unroll
                for (int i = 0; i < 6; i++) {
                    float a0 = 0.f, a1 = 0.f;
#pragma unroll
                    for (int cc = 0; cc < 8; cc += 2) {
                        float4 v0 = hv[cc], v1 = hv[cc + 1];
                        a0 += w[i][cc*4+0]*v0.x + w[i][cc*4+1]*v0.y + w[i][cc*4+2]*v0.z + w[i][cc*4+3]*v0.w;
                        a1 += w[i][cc*4+4]*v1.x + w[i][cc*4+5]*v1.y + w[i][cc*4+6]*v1.z + w[i][cc*4+7]*v1.w;
                    }
                    acc[i] = a0 + a1;
                }
#pragma unroll
                for (int i = 0; i < 6; i += 2) {
                    float2 p; p.x = acc[i]; p.y = acc[i + 1];
                    *reinterpret_cast<float2*>(&ps[q * G3 + row0 + i]) = p;
                }
                __syncthreads();
                // phase 2: reduce + gates
                if (tid < HID) {
                    int j = tid;
                    float ghr = (ps[j]         + ps[G3 + j])         + (ps[2*G3 + j]         + ps[3*G3 + j]);
                    float ghz = (ps[HID + j]   + ps[G3 + HID + j])   + (ps[2*G3 + HID + j]   + ps[3*G3 + HID + j]);
                    float ghn = (ps[2*HID + j] + ps[G3 + 2*HID + j]) + (ps[2*G3 + 2*HID + j] + ps[3*G3 + 2*HID + j]);
                    float r = fsig(gir + ghr + br);
                    float z = fsig(giz + ghz + bz);
                    float n = ftanh(gin + r * (ghn + bn));
                    float hn = (1.0f - z) * n + z * hprev;
                    hprev = hn;
                    h_s[j] = hn;
                    aux[s * HID + j] = hn;   // history in LDS, flushed per chunk
                    gir = n_gir; giz = n_giz; gin = n_gin;
                }
                __syncthreads();
            }
            // chunk flush: coalesced global write of CHUNK*128 floats
            {
                float4 v = *reinterpret_cast<const float4*>(&aux[tid * 4]);
                *reinterpret_cast<float4*>(&seq_o[(size_t)t0 * HID + tid * 4]) = v;
            }
            __syncthreads();
            if (tid == 0)
                __hip_atomic_store(out_flag, c + 1, __ATOMIC_RELEASE, __HIP_MEMORY_SCOPE_AGENT);
        }
    } else {
        // ---------------- gi role: layer l (1..3) ----------------
        const float* W   = WihR + (size_t)(l - 1) * G3 * HID;
        const float* seq_in = ws + GI_TOT + (size_t)(l - 1) * T_SEQ * HID;
        float* gi_o      = ws + (size_t)l * T_SEQ * G3;
        int* in_flag     = &fl[(4 + (l - 1)) * 16];   // seq_{l-1}
        int* out_flag    = &fl[l * 16];               // gi_l

        float w[6][32];
        const float* wbase = W + q * 32;
#pragma unroll
        for (int i = 0; i < 6; i++) {
            const float4* wr = reinterpret_cast<const float4*>(wbase + (size_t)(row0 + i) * HID);
#pragma unroll
            for (int c = 0; c < 8; c++) {
                float4 v = wr[c];
                w[i][c * 4 + 0] = v.x; w[i][c * 4 + 1] = v.y;
                w[i][c * 4 + 2] = v.z; w[i][c * 4 + 3] = v.w;
            }
        }
        float br = 0.f, bz = 0.f, bn = 0.f;
        if (tid < HID) {
            const float* bb = bih + (size_t)l * G3;
            br = bb[tid]; bz = bb[HID + tid]; bn = bb[2 * HID + tid];
        }

        for (int c = 0; c < NCHUNK; c++) {
            if (tid == 0) {
                while (__hip_atomic_load(in_flag, __ATOMIC_RELAXED, __HIP_MEMORY_SCOPE_AGENT) < c + 1)
                    __builtin_amdgcn_s_sleep(2);
            }
            __syncthreads();
            int t0 = c * CHUNK;
            // stage seq chunk (1024 floats) into aux: one float4 per thread
            {
                float4 v = *reinterpret_cast<const float4*>(&seq_in[(size_t)t0 * HID + tid * 4]);
                *reinterpret_cast<float4*>(&aux[tid * 4]) = v;
            }
            __syncthreads();
            for (int s = 0; s < CHUNK; s++) {
                int t = t0 + s;
                const float4* h4 = reinterpret_cast<const float4*>(aux + s * HID + q * 32);
                float4 hv[8];
#pragma unroll
                for (int cc = 0; cc < 8; cc++) hv[cc] = h4[cc];
                float acc[6];
#pragma unroll
                for (int i = 0; i < 6; i++) {
                    float a0 = 0.f, a1 = 0.f;
#pragma unroll
                    for (int cc = 0; cc < 8; cc += 2) {
                        float4 v0 = hv[cc], v1 = hv[cc + 1];
                        a0 += w[i][cc*4+0]*v0.x + w[i][cc*4+1]*v0.y + w[i][cc*4+2]*v0.z + w[i][cc*4+3]*v0.w;
                        a1 += w[i][cc*4+4]*v1.x + w[i][cc*4+5]*v1.y + w[i][cc*4+6]*v1.z + w[i][cc*4+7]*v1.w;
                    }
                    acc[i] = a0 + a1;
                }
#pragma unroll
                for (int i = 0; i < 6; i += 2) {
                    float2 p; p.x = acc[i]; p.y = acc[i + 1];
                    *reinterpret_cast<float2*>(&ps[q * G3 + row0 + i]) = p;
                }
                __syncthreads();
                if (tid < HID) {
                    int j = tid;
                    float vr = (ps[j]         + ps[G3 + j])         + (ps[2*G3 + j]         + ps[3*G3 + j]);
                    float vz = (ps[HID + j]   + ps[G3 + HID + j])   + (ps[2*G3 + HID + j]   + ps[3*G3 + HID + j]);
                    float vn = (ps[2*HID + j] + ps[G3 + 2*HID + j]) + (ps[2*G3 + 2*HID + j] + ps[3*G3 + 2*HID + j]);
                    float* gp = gi_o + (size_t)t * G3;
                    gp[j]           = vr + br;
                    gp[HID + j]     = vz + bz;
                    gp[2 * HID + j] = vn + bn;
                }
                __syncthreads();
            }
            __syncthreads();
            if (tid == 0)
                __hip_atomic_store(out_flag, c + 1, __ATOMIC_RELEASE, __HIP_MEMORY_SCOPE_AGENT);
        }
    }
}

// ---------------- FC head ----------------
__global__ void fc_kernel(const float* __restrict__ seq, const float* __restrict__ fc1w,
                          const float* __restrict__ fc1b, const float* __restrict__ fc2w,
                          const float* __restrict__ fc2b, float* __restrict__ out) {
    __shared__ float h3[HID];
    __shared__ float hid[HID];
    int t = blockIdx.x;
    int i = threadIdx.x;
    h3[i] = seq[t * HID + i];
    __syncthreads();
    const float4* w4 = reinterpret_cast<const float4*>(fc1w + i * HID);
    const float4* h4 = reinterpret_cast<const float4*>(h3);
    float a0 = 0.f, a1 = 0.f, a2 = 0.f, a3 = 0.f;
#pragma unroll
    for (int k = 0; k < 32; k += 4) {
        float4 w0 = w4[k], w1 = w4[k + 1], w2 = w4[k + 2], w3 = w4[k + 3];
        float4 h0 = h4[k], h1 = h4[k + 1], h2 = h4[k + 2], h3v = h4[k + 3];
        a0 += w0.x * h0.x + w0.y * h0.y + w0.z * h0.z + w0.w * h0.w;
        a1 += w1.x * h1.x + w1.y * h1.y + w1.z * h1.z + w1.w * h1.w;
        a2 += w2.x * h2.x + w2.y * h2.y + w2.z * h2.z + w2.w * h2.w;
        a3 += w3.x * h3v.x + w3.y * h3v.y + w3.z * h3v.z + w3.w * h3v.w;
    }
    float v = fc1b[i] + ((a0 + a1) + (a2 + a3));
    hid[i] = v > 0.0f ? v : 0.0f;
    __syncthreads();
    if (i < 3) {
        const float* w = fc2w + i * HID;
        float s = 0.f;
#pragma unroll
        for (int k = 0; k < HID; k++) s += w[k] * hid[k];
        out[t * 3 + i] = fc2b[i] + s;
    }
}

extern "C" void kernel_launch(void* const* d_in, const int* in_sizes, int n_in,
                              void* d_out, int out_size, void* d_ws, size_t ws_size,
                              hipStream_t stream) {
    const float* x     = (const float*)d_in[0];
    const float* Wih0  = (const float*)d_in[1];
    const float* WihR  = (const float*)d_in[2];   // (3, 384, 128)
    const float* Whh   = (const float*)d_in[3];   // (4, 384, 128)
    const float* bih   = (const float*)d_in[4];   // (4, 384)
    const float* bhh   = (const float*)d_in[5];   // (4, 384)
    const float* fc1w  = (const float*)d_in[6];
    const float* fc1b  = (const float*)d_in[7];
    const float* fc2w  = (const float*)d_in[8];
    const float* fc2b  = (const float*)d_in[9];
    float* out = (float*)d_out;
    float* ws  = (float*)d_ws;

    int*   flags = (int*)(ws + FLAG_OFF);
    float* gi0   = ws;
    float* seq3  = ws + GI_TOT + (size_t)3 * T_SEQ * HID;

    init_flags<<<1, 64, 0, stream>>>(flags);
    gi0_kernel<<<T_SEQ, G3, 0, stream>>>(x, Wih0, bih, gi0);
    pipe_kernel<<<7, 256, 0, stream>>>(ws, WihR, bih, Whh, bhh);
    fc_kernel<<<T_SEQ, HID, 0, stream>>>(seq3, fc1w, fc1b, fc2w, fc2b, out);
}